// Round 1
// baseline (1033.654 us; speedup 1.0000x reference)
//
#include <hip/hip_runtime.h>
#include <hip/hip_bf16.h>
#include <stdint.h>
#include <math.h>

// ---- problem dims (fixed by reference) ----
#define H_DIM 2048
#define I_DIM 1408
#define E_NUM 16
#define IS_DIM 2816
#define T_NUM 2048      // B*S tokens
#define A_NUM 4096      // T*K assignments

typedef float f32x4 __attribute__((ext_vector_type(4)));
typedef __bf16 bf16x8 __attribute__((ext_vector_type(8)));
typedef __bf16 bf16x4 __attribute__((ext_vector_type(4)));

// async global->LDS 16B (dwordx4). LDS dest is wave-uniform base + lane*16.
__device__ __forceinline__ void async16(const __bf16* g, __bf16* l) {
  __builtin_amdgcn_global_load_lds((__attribute__((address_space(1))) void*)g,
                                   (__attribute__((address_space(3))) void*)l,
                                   16, 0, 0);
}

// ---- fp32 -> bf16 convert of hidden states ----
__global__ __launch_bounds__(256) void k_convert_x(const float* __restrict__ x,
                                                   __bf16* __restrict__ xb) {
  int i = (blockIdx.x * 256 + threadIdx.x) * 4;
  float4 v = *(const float4*)(x + i);
  bf16x4 o;
  o[0] = (__bf16)v.x; o[1] = (__bf16)v.y; o[2] = (__bf16)v.z; o[3] = (__bf16)v.w;
  *(bf16x4*)(xb + i) = o;
}

// ---- router: fp32 logits, softmax, top-2 (tie -> lower index, like jax top_k) ----
__global__ __launch_bounds__(256) void k_router(const float* __restrict__ x,
                                                const float* __restrict__ gw,
                                                int* __restrict__ tki,
                                                float* __restrict__ tkw) {
  __shared__ float red[E_NUM * 256];
  __shared__ float st[256];
  __shared__ float sc[E_NUM];
  int t = blockIdx.x, tid = threadIdx.x;
  const float* xr = x + (size_t)t * H_DIM + tid * 8;
  float4 xv0 = *(const float4*)xr;
  float4 xv1 = *(const float4*)(xr + 4);
#pragma unroll
  for (int e = 0; e < E_NUM; e++) {
    const float* g = gw + e * H_DIM + tid * 8;
    float4 a = *(const float4*)g;
    float4 b = *(const float4*)(g + 4);
    red[e * 256 + tid] = xv0.x * a.x + xv0.y * a.y + xv0.z * a.z + xv0.w * a.w +
                         xv1.x * b.x + xv1.y * b.y + xv1.z * b.z + xv1.w * b.w;
  }
  __syncthreads();
  {
    int e = tid >> 4, j = tid & 15;
    float s = 0.f;
#pragma unroll
    for (int m = 0; m < 16; m++) s += red[e * 256 + m * 16 + j];
    st[e * 16 + j] = s;
  }
  __syncthreads();
  if (tid < E_NUM) {
    float s = 0.f;
#pragma unroll
    for (int m = 0; m < 16; m++) s += st[tid * 16 + m];
    sc[tid] = s;
  }
  __syncthreads();
  if (tid == 0) {
    int i1 = 0;
    for (int q = 1; q < E_NUM; q++) if (sc[q] > sc[i1]) i1 = q;
    int i2 = (i1 == 0) ? 1 : 0;
    for (int q = 0; q < E_NUM; q++) if (q != i1 && sc[q] > sc[i2]) i2 = q;
    float mx = sc[i1], Z = 0.f;
    for (int q = 0; q < E_NUM; q++) Z += expf(sc[q] - mx);
    tki[t * 2] = i1;
    tki[t * 2 + 1] = i2;
    tkw[t * 2] = 1.0f / Z;                 // exp(0)/Z
    tkw[t * 2 + 1] = expf(sc[i2] - mx) / Z;
  }
}

// ---- dispatch: counts -> group offsets; also zero-page + shared group table ----
__global__ __launch_bounds__(256) void k_count(const int* __restrict__ tki,
                                               int* __restrict__ grp,
                                               int* __restrict__ cur,
                                               int* __restrict__ grps,
                                               __bf16* __restrict__ zb) {
  __shared__ int cnt[E_NUM];
  int tid = threadIdx.x;
  if (tid < E_NUM) cnt[tid] = 0;
  __syncthreads();
  for (int i = tid; i < A_NUM; i += 256) atomicAdd(&cnt[tki[i]], 1);
  __syncthreads();
  if (tid == 0) {
    int off = 0;
    for (int e = 0; e < E_NUM; e++) { grp[e] = off; cur[e] = off; off += cnt[e]; }
    grp[E_NUM] = off;
    grps[0] = 0; grps[1] = T_NUM;
  }
  if (tid < 64) zb[tid] = (__bf16)0.f;     // 128B zero page for OOB staging
}

__global__ __launch_bounds__(256) void k_fill(const int* __restrict__ tki,
                                              int* __restrict__ cur,
                                              int* __restrict__ slot_of,
                                              int* __restrict__ tok_of) {
  int i = blockIdx.x * 256 + threadIdx.x;
  if (i < A_NUM) {
    int e = tki[i];
    int s = atomicAdd(&cur[e], 1);
    slot_of[i] = s;
    tok_of[s] = i >> 1;
  }
}

// ---- gather token rows (bf16) into expert-sorted buffer ----
__global__ __launch_bounds__(256) void k_gather(const __bf16* __restrict__ xb,
                                                const int* __restrict__ tok_of,
                                                __bf16* __restrict__ buf) {
  int gid = blockIdx.x * 256 + threadIdx.x;
  int s = gid >> 8;            // 256 x 16B chunks per row (H=2048)
  int off = (gid & 255) * 8;
  int t = tok_of[s];
  *(uint4*)(buf + (size_t)s * H_DIM + off) = *(const uint4*)(xb + (size_t)t * H_DIM + off);
}

// ---- fp32 [z][R][C] -> bf16 [z][C][R] (weights to B^T layout for MFMA) ----
__global__ __launch_bounds__(256) void k_transpose(const float* __restrict__ in,
                                                   __bf16* __restrict__ out,
                                                   int R, int C) {
  __shared__ float tile[32][33];
  size_t zb = (size_t)blockIdx.z * R * C;
  int c0 = blockIdx.x * 32, r0 = blockIdx.y * 32;
  int x = threadIdx.x, y = threadIdx.y;
#pragma unroll
  for (int i = 0; i < 4; i++)
    tile[y + 8 * i][x] = in[zb + (size_t)(r0 + y + 8 * i) * C + c0 + x];
  __syncthreads();
#pragma unroll
  for (int i = 0; i < 4; i++)
    out[zb + (size_t)(c0 + y + 8 * i) * R + r0 + x] = (__bf16)tile[x][y + 8 * i];
}

// ---- grouped bf16 GEMM: C[M][N] = A[M][K] * B^T[g][N][K], m97-style ----
// grid: (N/128, maxMtilesPerGroup, nGroups); block 256 (4 waves, 2x2 of 64x64)
__global__ __launch_bounds__(256) void k_gemm(const __bf16* __restrict__ A,
                                              const __bf16* __restrict__ Bt,
                                              __bf16* __restrict__ C,
                                              const int* __restrict__ grp,
                                              const __bf16* __restrict__ zb,
                                              int K, int N) {
  int g = blockIdx.z;
  int mstart = grp[g], mend = grp[g + 1];
  int m0 = mstart + blockIdx.y * 128;
  if (m0 >= mend) return;
  int n0 = blockIdx.x * 128;
  const __bf16* Bg = Bt + (size_t)g * N * K;

  __shared__ __align__(16) __bf16 As[128 * 32];
  __shared__ __align__(16) __bf16 Bs[128 * 32];

  int tid = threadIdx.x;
  int wave = tid >> 6, lane = tid & 63;
  int srow = wave * 16 + (lane >> 2);   // staging row (call 1); +64 for call 2
  int scol = (lane & 3) * 8;            // k element offset within BK=32

  int rA1 = m0 + srow, rA2 = m0 + srow + 64;
  bool okA1 = rA1 < mend, okA2 = rA2 < mend;
  const __bf16* baseA1 = A + (size_t)rA1 * K + scol;
  const __bf16* baseA2 = A + (size_t)rA2 * K + scol;
  const __bf16* baseB1 = Bg + (size_t)(n0 + srow) * K + scol;
  const __bf16* baseB2 = Bg + (size_t)(n0 + srow + 64) * K + scol;

  __bf16* ldsA1 = As + wave * 512;        // wave-uniform LDS bases (1KB/wave)
  __bf16* ldsA2 = As + 2048 + wave * 512;
  __bf16* ldsB1 = Bs + wave * 512;
  __bf16* ldsB2 = Bs + 2048 + wave * 512;

  int wm = (wave >> 1) * 64, wn = (wave & 1) * 64;
  int r16 = lane & 15, quad = lane >> 4;

  f32x4 acc[4][4] = {};
  for (int k0 = 0; k0 < K; k0 += 32) {
    __syncthreads();
    async16(okA1 ? baseA1 + k0 : zb, ldsA1);
    async16(okA2 ? baseA2 + k0 : zb, ldsA2);
    async16(baseB1 + k0, ldsB1);
    async16(baseB2 + k0, ldsB2);
    __syncthreads();
    bf16x8 af[4], bq[4];
#pragma unroll
    for (int i = 0; i < 4; i++)
      af[i] = *(const bf16x8*)(As + (wm + i * 16 + r16) * 32 + quad * 8);
#pragma unroll
    for (int i = 0; i < 4; i++)
      bq[i] = *(const bf16x8*)(Bs + (wn + i * 16 + r16) * 32 + quad * 8);
#pragma unroll
    for (int mi = 0; mi < 4; mi++)
#pragma unroll
      for (int ni = 0; ni < 4; ni++)
        acc[mi][ni] = __builtin_amdgcn_mfma_f32_16x16x32_bf16(af[mi], bq[ni],
                                                              acc[mi][ni], 0, 0, 0);
  }
  // epilogue: D row = quad*4+reg, col = lane&15 (verified m89/m91 layout)
#pragma unroll
  for (int mi = 0; mi < 4; mi++) {
    int row_base = m0 + wm + mi * 16 + quad * 4;
#pragma unroll
    for (int r = 0; r < 4; r++) {
      int row = row_base + r;
      if (row < mend) {
#pragma unroll
        for (int ni = 0; ni < 4; ni++) {
          int col = n0 + wn + ni * 16 + r16;
          C[(size_t)row * N + col] = (__bf16)acc[mi][ni][r];
        }
      }
    }
  }
}

// ---- elementwise silu(g)*u in fp32, bf16 in/out ----
__global__ __launch_bounds__(256) void k_silu_mul(const __bf16* __restrict__ G,
                                                  const __bf16* __restrict__ U,
                                                  __bf16* __restrict__ M) {
  int i = (blockIdx.x * 256 + threadIdx.x) * 4;
  bf16x4 g = *(const bf16x4*)(G + i);
  bf16x4 u = *(const bf16x4*)(U + i);
  bf16x4 o;
#pragma unroll
  for (int j = 0; j < 4; j++) {
    float gv = (float)g[j], uv = (float)u[j];
    float s = gv / (1.f + expf(-gv));
    o[j] = (__bf16)(s * uv);
  }
  *(bf16x4*)(M + i) = o;
}

// ---- combine: out = shared + w1*eo[slot1] + w2*eo[slot2] (fp32 out) ----
__global__ __launch_bounds__(256) void k_combine(const __bf16* __restrict__ SH,
                                                 const __bf16* __restrict__ EO,
                                                 const int* __restrict__ slot_of,
                                                 const float* __restrict__ tkw,
                                                 float* __restrict__ out) {
  int gid = blockIdx.x * 256 + threadIdx.x;
  int t = gid >> 9;            // 512 float4 chunks per row
  int c = (gid & 511) * 4;
  int s1 = slot_of[t * 2], s2 = slot_of[t * 2 + 1];
  float w1 = tkw[t * 2], w2 = tkw[t * 2 + 1];
  bf16x4 sh = *(const bf16x4*)(SH + (size_t)t * H_DIM + c);
  bf16x4 e1 = *(const bf16x4*)(EO + (size_t)s1 * H_DIM + c);
  bf16x4 e2 = *(const bf16x4*)(EO + (size_t)s2 * H_DIM + c);
  float4 o;
  o.x = (float)sh[0] + w1 * (float)e1[0] + w2 * (float)e2[0];
  o.y = (float)sh[1] + w1 * (float)e1[1] + w2 * (float)e2[1];
  o.z = (float)sh[2] + w1 * (float)e1[2] + w2 * (float)e2[2];
  o.w = (float)sh[3] + w1 * (float)e1[3] + w2 * (float)e2[3];
  *(float4*)(out + (size_t)t * H_DIM + c) = o;
}

extern "C" void kernel_launch(void* const* d_in, const int* in_sizes, int n_in,
                              void* d_out, int out_size, void* d_ws, size_t ws_size,
                              hipStream_t stream) {
  const float* x       = (const float*)d_in[0];
  const float* gate_w  = (const float*)d_in[1];
  const float* w_gate  = (const float*)d_in[2];
  const float* w_up    = (const float*)d_in[3];
  const float* w_down  = (const float*)d_in[4];
  const float* ws_gate = (const float*)d_in[5];
  const float* ws_up   = (const float*)d_in[6];
  const float* ws_down = (const float*)d_in[7];
  float* out = (float*)d_out;

  char* p = (char*)d_ws;
  auto alloc = [&](size_t bytes) {
    char* r = p;
    p += (bytes + 255) & ~(size_t)255;
    return r;
  };
  __bf16* WT   = (__bf16*)alloc((size_t)E_NUM * H_DIM * I_DIM * 2);  // 92.3 MB, reused per weight
  __bf16* XB   = (__bf16*)alloc((size_t)T_NUM * H_DIM * 2);
  __bf16* BUF  = (__bf16*)alloc((size_t)A_NUM * H_DIM * 2);
  __bf16* G    = (__bf16*)alloc((size_t)A_NUM * I_DIM * 2);          // == T*IS elems, reused
  __bf16* U    = (__bf16*)alloc((size_t)A_NUM * I_DIM * 2);
  __bf16* M    = (__bf16*)alloc((size_t)A_NUM * I_DIM * 2);
  __bf16* EO   = (__bf16*)alloc((size_t)A_NUM * H_DIM * 2);
  __bf16* SH   = (__bf16*)alloc((size_t)T_NUM * H_DIM * 2);
  int* TKI     = (int*)alloc(A_NUM * 4);
  float* TKW   = (float*)alloc(A_NUM * 4);
  int* GRP     = (int*)alloc(128);
  int* GRPS    = (int*)alloc(128);
  int* CUR     = (int*)alloc(128);
  int* SLOT    = (int*)alloc(A_NUM * 4);
  int* TOK     = (int*)alloc(A_NUM * 4);
  __bf16* ZB   = (__bf16*)alloc(256);
  if ((size_t)(p - (char*)d_ws) > ws_size) return;  // ws too small: bail

  // prologue: convert, route, dispatch, gather
  k_convert_x<<<4096, 256, 0, stream>>>(x, XB);
  k_router<<<2048, 256, 0, stream>>>(x, gate_w, TKI, TKW);
  k_count<<<1, 256, 0, stream>>>(TKI, GRP, CUR, GRPS, ZB);
  k_fill<<<16, 256, 0, stream>>>(TKI, CUR, SLOT, TOK);
  k_gather<<<4096, 256, 0, stream>>>(XB, TOK, BUF);

  // routed experts
  k_transpose<<<dim3(44, 64, 16), dim3(32, 8), 0, stream>>>(w_gate, WT, 2048, 1408);
  k_gemm<<<dim3(11, 8, 16), 256, 0, stream>>>(BUF, WT, G, GRP, ZB, 2048, 1408);
  k_transpose<<<dim3(44, 64, 16), dim3(32, 8), 0, stream>>>(w_up, WT, 2048, 1408);
  k_gemm<<<dim3(11, 8, 16), 256, 0, stream>>>(BUF, WT, U, GRP, ZB, 2048, 1408);
  k_silu_mul<<<5632, 256, 0, stream>>>(G, U, M);
  k_transpose<<<dim3(64, 44, 16), dim3(32, 8), 0, stream>>>(w_down, WT, 1408, 2048);
  k_gemm<<<dim3(16, 8, 16), 256, 0, stream>>>(M, WT, EO, GRP, ZB, 1408, 2048);

  // shared experts (reuse G/U/M: identical byte sizes)
  k_transpose<<<dim3(88, 64, 1), dim3(32, 8), 0, stream>>>(ws_gate, WT, 2048, 2816);
  k_gemm<<<dim3(22, 16, 1), 256, 0, stream>>>(XB, WT, G, GRPS, ZB, 2048, 2816);
  k_transpose<<<dim3(88, 64, 1), dim3(32, 8), 0, stream>>>(ws_up, WT, 2048, 2816);
  k_gemm<<<dim3(22, 16, 1), 256, 0, stream>>>(XB, WT, U, GRPS, ZB, 2048, 2816);
  k_silu_mul<<<5632, 256, 0, stream>>>(G, U, M);
  k_transpose<<<dim3(64, 88, 1), dim3(32, 8), 0, stream>>>(ws_down, WT, 2816, 2048);
  k_gemm<<<dim3(16, 16, 1), 256, 0, stream>>>(M, WT, SH, GRPS, ZB, 2816, 2048);

  // combine
  k_combine<<<4096, 256, 0, stream>>>(SH, EO, SLOT, TKW, out);
}

// Round 2
// 933.514 us; speedup vs baseline: 1.1073x; 1.1073x over previous
//
#include <hip/hip_runtime.h>
#include <hip/hip_bf16.h>
#include <stdint.h>
#include <math.h>

// ---- problem dims (fixed by reference) ----
#define H_DIM 2048
#define I_DIM 1408
#define E_NUM 16
#define IS_DIM 2816
#define T_NUM 2048      // B*S tokens
#define A_NUM 4096      // T*K assignments

typedef float f32x4 __attribute__((ext_vector_type(4)));
typedef __bf16 bf16x8 __attribute__((ext_vector_type(8)));
typedef __bf16 bf16x4 __attribute__((ext_vector_type(4)));

// async global->LDS 16B (dwordx4). LDS dest is wave-uniform base + lane*16.
__device__ __forceinline__ void async16(const __bf16* g, __bf16* l) {
  __builtin_amdgcn_global_load_lds((__attribute__((address_space(1))) void*)g,
                                   (__attribute__((address_space(3))) void*)l,
                                   16, 0, 0);
}

__device__ __forceinline__ float silu_f(float g) {
  return g / (1.f + __expf(-g));
}

// ---- fp32 -> bf16 convert of hidden states ----
__global__ __launch_bounds__(256) void k_convert_x(const float* __restrict__ x,
                                                   __bf16* __restrict__ xb) {
  int i = (blockIdx.x * 256 + threadIdx.x) * 4;
  float4 v = *(const float4*)(x + i);
  bf16x4 o;
  o[0] = (__bf16)v.x; o[1] = (__bf16)v.y; o[2] = (__bf16)v.z; o[3] = (__bf16)v.w;
  *(bf16x4*)(xb + i) = o;
}

// ---- router: fp32 logits, softmax, top-2 ----
__global__ __launch_bounds__(256) void k_router(const float* __restrict__ x,
                                                const float* __restrict__ gw,
                                                int* __restrict__ tki,
                                                float* __restrict__ tkw) {
  __shared__ float red[E_NUM * 256];
  __shared__ float st[256];
  __shared__ float sc[E_NUM];
  int t = blockIdx.x, tid = threadIdx.x;
  const float* xr = x + (size_t)t * H_DIM + tid * 8;
  float4 xv0 = *(const float4*)xr;
  float4 xv1 = *(const float4*)(xr + 4);
#pragma unroll
  for (int e = 0; e < E_NUM; e++) {
    const float* g = gw + e * H_DIM + tid * 8;
    float4 a = *(const float4*)g;
    float4 b = *(const float4*)(g + 4);
    red[e * 256 + tid] = xv0.x * a.x + xv0.y * a.y + xv0.z * a.z + xv0.w * a.w +
                         xv1.x * b.x + xv1.y * b.y + xv1.z * b.z + xv1.w * b.w;
  }
  __syncthreads();
  {
    int e = tid >> 4, j = tid & 15;
    float s = 0.f;
#pragma unroll
    for (int m = 0; m < 16; m++) s += red[e * 256 + m * 16 + j];
    st[e * 16 + j] = s;
  }
  __syncthreads();
  if (tid < E_NUM) {
    float s = 0.f;
#pragma unroll
    for (int m = 0; m < 16; m++) s += st[tid * 16 + m];
    sc[tid] = s;
  }
  __syncthreads();
  if (tid == 0) {
    int i1 = 0;
    for (int q = 1; q < E_NUM; q++) if (sc[q] > sc[i1]) i1 = q;
    int i2 = (i1 == 0) ? 1 : 0;
    for (int q = 0; q < E_NUM; q++) if (q != i1 && sc[q] > sc[i2]) i2 = q;
    float mx = sc[i1], Z = 0.f;
    for (int q = 0; q < E_NUM; q++) Z += expf(sc[q] - mx);
    tki[t * 2] = i1;
    tki[t * 2 + 1] = i2;
    tkw[t * 2] = 1.0f / Z;
    tkw[t * 2 + 1] = expf(sc[i2] - mx) / Z;
  }
}

// ---- dispatch: count + offsets + slot fill, single block ----
__global__ __launch_bounds__(256) void k_dispatch(const int* __restrict__ tki,
                                                  int* __restrict__ grp,
                                                  int* __restrict__ grps,
                                                  int* __restrict__ slot_of,
                                                  int* __restrict__ tok_of,
                                                  __bf16* __restrict__ zb) {
  __shared__ int cnt[E_NUM];
  __shared__ int cur[E_NUM];
  int tid = threadIdx.x;
  if (tid < E_NUM) cnt[tid] = 0;
  __syncthreads();
  for (int i = tid; i < A_NUM; i += 256) atomicAdd(&cnt[tki[i]], 1);
  __syncthreads();
  if (tid == 0) {
    int off = 0;
    for (int e = 0; e < E_NUM; e++) { grp[e] = off; cur[e] = off; off += cnt[e]; }
    grp[E_NUM] = off;
    grps[0] = 0; grps[1] = T_NUM;
  }
  if (tid < 64) zb[tid] = (__bf16)0.f;    // 128B zero page for OOB staging
  __syncthreads();
  for (int i = tid; i < A_NUM; i += 256) {
    int e = tki[i];
    int s = atomicAdd(&cur[e], 1);
    slot_of[i] = s;
    tok_of[s] = i >> 1;
  }
}

// ---- gather token rows (bf16) into expert-sorted buffer ----
__global__ __launch_bounds__(256) void k_gather(const __bf16* __restrict__ xb,
                                                const int* __restrict__ tok_of,
                                                __bf16* __restrict__ buf) {
  int gid = blockIdx.x * 256 + threadIdx.x;
  int s = gid >> 8;            // 256 x 16B chunks per row (H=2048)
  int off = (gid & 255) * 8;
  int t = tok_of[s];
  *(uint4*)(buf + (size_t)s * H_DIM + off) = *(const uint4*)(xb + (size_t)t * H_DIM + off);
}

// ---- fp32 [z][R][C] -> bf16 [z][C][R], 64x64 tiles, full-wave coalescing ----
__global__ __launch_bounds__(256) void k_transpose(const float* __restrict__ in,
                                                   __bf16* __restrict__ out,
                                                   int R, int C) {
  __shared__ float tile[64][65];
  size_t zb = (size_t)blockIdx.z * R * C;
  int c0 = blockIdx.x * 64, r0 = blockIdx.y * 64;
  int x = threadIdx.x, y = threadIdx.y;   // block (64,4)
#pragma unroll
  for (int i = 0; i < 16; i++)
    tile[y + 4 * i][x] = in[zb + (size_t)(r0 + y + 4 * i) * C + c0 + x];
  __syncthreads();
#pragma unroll
  for (int i = 0; i < 16; i++)
    out[zb + (size_t)(c0 + y + 4 * i) * R + r0 + x] = (__bf16)tile[x][y + 4 * i];
}

// ---- fused gate+up grouped GEMM + silu epilogue ----
// M128 x N64(gate)+N64(up) tile; A[M][K] bf16, Bg/Bu = [g][N][K] bf16 (B^T)
// out Mbuf[m][n] = silu(A.Bg^T) * (A.Bu^T); grid (N/64, mTilesMax, groups)
__global__ __launch_bounds__(256) void k_gemm_gu(const __bf16* __restrict__ A,
                                                 const __bf16* __restrict__ Bg,
                                                 const __bf16* __restrict__ Bu,
                                                 __bf16* __restrict__ Mb,
                                                 const int* __restrict__ grp,
                                                 const __bf16* __restrict__ zb,
                                                 int K, int N) {
  int g = blockIdx.z;
  int mstart = grp[g], mend = grp[g + 1];
  int m0 = mstart + blockIdx.y * 128;
  if (m0 >= mend) return;
  int n0 = blockIdx.x * 64;
  const __bf16* Bgg = Bg + (size_t)g * N * K;
  const __bf16* Bug = Bu + (size_t)g * N * K;

  __shared__ __align__(16) __bf16 As[128 * 32];   // 8 KB
  __shared__ __align__(16) __bf16 Gs[64 * 32];    // 4 KB
  __shared__ __align__(16) __bf16 Us[64 * 32];    // 4 KB

  int tid = threadIdx.x;
  int wave = tid >> 6, lane = tid & 63;
  int srow = wave * 16 + (lane >> 2);
  int scol = (lane & 3) * 8;

  int rA1 = m0 + srow, rA2 = m0 + srow + 64;
  bool okA1 = rA1 < mend, okA2 = rA2 < mend;
  const __bf16* baseA1 = A + (size_t)rA1 * K + scol;
  const __bf16* baseA2 = A + (size_t)rA2 * K + scol;
  const __bf16* baseG = Bgg + (size_t)(n0 + srow) * K + scol;
  const __bf16* baseU = Bug + (size_t)(n0 + srow) * K + scol;

  __bf16* ldsA1 = As + wave * 512;
  __bf16* ldsA2 = As + 2048 + wave * 512;
  __bf16* ldsG = Gs + wave * 512;
  __bf16* ldsU = Us + wave * 512;

  int wm = (wave >> 1) * 64, wn = (wave & 1) * 32;
  int r16 = lane & 15, quad = lane >> 4;

  f32x4 accg[4][2] = {}, accu[4][2] = {};
  for (int k0 = 0; k0 < K; k0 += 32) {
    __syncthreads();
    async16(okA1 ? baseA1 + k0 : zb, ldsA1);
    async16(okA2 ? baseA2 + k0 : zb, ldsA2);
    async16(baseG + k0, ldsG);
    async16(baseU + k0, ldsU);
    __syncthreads();
    bf16x8 af[4], bg[2], bu[2];
#pragma unroll
    for (int i = 0; i < 4; i++)
      af[i] = *(const bf16x8*)(As + (wm + i * 16 + r16) * 32 + quad * 8);
#pragma unroll
    for (int i = 0; i < 2; i++) {
      bg[i] = *(const bf16x8*)(Gs + (wn + i * 16 + r16) * 32 + quad * 8);
      bu[i] = *(const bf16x8*)(Us + (wn + i * 16 + r16) * 32 + quad * 8);
    }
#pragma unroll
    for (int mi = 0; mi < 4; mi++)
#pragma unroll
      for (int ni = 0; ni < 2; ni++) {
        accg[mi][ni] = __builtin_amdgcn_mfma_f32_16x16x32_bf16(af[mi], bg[ni],
                                                               accg[mi][ni], 0, 0, 0);
        accu[mi][ni] = __builtin_amdgcn_mfma_f32_16x16x32_bf16(af[mi], bu[ni],
                                                               accu[mi][ni], 0, 0, 0);
      }
  }
  // D layout: row = quad*4 + reg, col = lane&15
#pragma unroll
  for (int mi = 0; mi < 4; mi++) {
    int row_base = m0 + wm + mi * 16 + quad * 4;
#pragma unroll
    for (int r = 0; r < 4; r++) {
      int row = row_base + r;
      if (row < mend) {
#pragma unroll
        for (int ni = 0; ni < 2; ni++) {
          int col = n0 + wn + ni * 16 + r16;
          float v = silu_f(accg[mi][ni][r]) * accu[mi][ni][r];
          Mb[(size_t)row * N + col] = (__bf16)v;
        }
      }
    }
  }
}

// ---- grouped GEMM 128x64: C = A * B^T ----
__global__ __launch_bounds__(256) void k_gemm_dn(const __bf16* __restrict__ A,
                                                 const __bf16* __restrict__ Bt,
                                                 __bf16* __restrict__ C,
                                                 const int* __restrict__ grp,
                                                 const __bf16* __restrict__ zb,
                                                 int K, int N) {
  int g = blockIdx.z;
  int mstart = grp[g], mend = grp[g + 1];
  int m0 = mstart + blockIdx.y * 128;
  if (m0 >= mend) return;
  int n0 = blockIdx.x * 64;
  const __bf16* Bg = Bt + (size_t)g * N * K;

  __shared__ __align__(16) __bf16 As[128 * 32];
  __shared__ __align__(16) __bf16 Bs[64 * 32];

  int tid = threadIdx.x;
  int wave = tid >> 6, lane = tid & 63;
  int srow = wave * 16 + (lane >> 2);
  int scol = (lane & 3) * 8;

  int rA1 = m0 + srow, rA2 = m0 + srow + 64;
  bool okA1 = rA1 < mend, okA2 = rA2 < mend;
  const __bf16* baseA1 = A + (size_t)rA1 * K + scol;
  const __bf16* baseA2 = A + (size_t)rA2 * K + scol;
  const __bf16* baseB = Bg + (size_t)(n0 + srow) * K + scol;

  __bf16* ldsA1 = As + wave * 512;
  __bf16* ldsA2 = As + 2048 + wave * 512;
  __bf16* ldsB = Bs + wave * 512;

  int wm = (wave >> 1) * 64, wn = (wave & 1) * 32;
  int r16 = lane & 15, quad = lane >> 4;

  f32x4 acc[4][2] = {};
  for (int k0 = 0; k0 < K; k0 += 32) {
    __syncthreads();
    async16(okA1 ? baseA1 + k0 : zb, ldsA1);
    async16(okA2 ? baseA2 + k0 : zb, ldsA2);
    async16(baseB + k0, ldsB);
    __syncthreads();
    bf16x8 af[4], bq[2];
#pragma unroll
    for (int i = 0; i < 4; i++)
      af[i] = *(const bf16x8*)(As + (wm + i * 16 + r16) * 32 + quad * 8);
#pragma unroll
    for (int i = 0; i < 2; i++)
      bq[i] = *(const bf16x8*)(Bs + (wn + i * 16 + r16) * 32 + quad * 8);
#pragma unroll
    for (int mi = 0; mi < 4; mi++)
#pragma unroll
      for (int ni = 0; ni < 2; ni++)
        acc[mi][ni] = __builtin_amdgcn_mfma_f32_16x16x32_bf16(af[mi], bq[ni],
                                                              acc[mi][ni], 0, 0, 0);
  }
#pragma unroll
  for (int mi = 0; mi < 4; mi++) {
    int row_base = m0 + wm + mi * 16 + quad * 4;
#pragma unroll
    for (int r = 0; r < 4; r++) {
      int row = row_base + r;
      if (row < mend) {
#pragma unroll
        for (int ni = 0; ni < 2; ni++) {
          int col = n0 + wn + ni * 16 + r16;
          C[(size_t)row * N + col] = (__bf16)acc[mi][ni][r];
        }
      }
    }
  }
}

// ---- combine: out = shared + w1*eo[slot1] + w2*eo[slot2] (fp32 out) ----
__global__ __launch_bounds__(256) void k_combine(const __bf16* __restrict__ SH,
                                                 const __bf16* __restrict__ EO,
                                                 const int* __restrict__ slot_of,
                                                 const float* __restrict__ tkw,
                                                 float* __restrict__ out) {
  int gid = blockIdx.x * 256 + threadIdx.x;
  int t = gid >> 9;
  int c = (gid & 511) * 4;
  int s1 = slot_of[t * 2], s2 = slot_of[t * 2 + 1];
  float w1 = tkw[t * 2], w2 = tkw[t * 2 + 1];
  bf16x4 sh = *(const bf16x4*)(SH + (size_t)t * H_DIM + c);
  bf16x4 e1 = *(const bf16x4*)(EO + (size_t)s1 * H_DIM + c);
  bf16x4 e2 = *(const bf16x4*)(EO + (size_t)s2 * H_DIM + c);
  float4 o;
  o.x = (float)sh[0] + w1 * (float)e1[0] + w2 * (float)e2[0];
  o.y = (float)sh[1] + w1 * (float)e1[1] + w2 * (float)e2[1];
  o.z = (float)sh[2] + w1 * (float)e1[2] + w2 * (float)e2[2];
  o.w = (float)sh[3] + w1 * (float)e1[3] + w2 * (float)e2[3];
  *(float4*)(out + (size_t)t * H_DIM + c) = o;
}

extern "C" void kernel_launch(void* const* d_in, const int* in_sizes, int n_in,
                              void* d_out, int out_size, void* d_ws, size_t ws_size,
                              hipStream_t stream) {
  const float* x       = (const float*)d_in[0];
  const float* gate_w  = (const float*)d_in[1];
  const float* w_gate  = (const float*)d_in[2];
  const float* w_up    = (const float*)d_in[3];
  const float* w_down  = (const float*)d_in[4];
  const float* ws_gate = (const float*)d_in[5];
  const float* ws_up   = (const float*)d_in[6];
  const float* ws_down = (const float*)d_in[7];
  float* out = (float*)d_out;

  char* p = (char*)d_ws;
  auto alloc = [&](size_t bytes) {
    char* r = p;
    p += (bytes + 255) & ~(size_t)255;
    return r;
  };
  __bf16* WT1  = (__bf16*)alloc((size_t)E_NUM * H_DIM * I_DIM * 2);  // 92.3 MB
  __bf16* WT2  = (__bf16*)alloc((size_t)E_NUM * H_DIM * I_DIM * 2);  // 92.3 MB
  __bf16* XB   = (__bf16*)alloc((size_t)T_NUM * H_DIM * 2);
  __bf16* BUF  = (__bf16*)alloc((size_t)A_NUM * H_DIM * 2);
  __bf16* Mb   = (__bf16*)alloc((size_t)A_NUM * I_DIM * 2);          // == T*IS, reused
  __bf16* EO   = (__bf16*)alloc((size_t)A_NUM * H_DIM * 2);
  __bf16* SH   = (__bf16*)alloc((size_t)T_NUM * H_DIM * 2);
  int* TKI     = (int*)alloc(A_NUM * 4);
  float* TKW   = (float*)alloc(A_NUM * 4);
  int* GRP     = (int*)alloc(128);
  int* GRPS    = (int*)alloc(128);
  int* SLOT    = (int*)alloc(A_NUM * 4);
  int* TOK     = (int*)alloc(A_NUM * 4);
  __bf16* ZB   = (__bf16*)alloc(256);
  if ((size_t)(p - (char*)d_ws) > ws_size) return;

  // prologue
  k_convert_x<<<4096, 256, 0, stream>>>(x, XB);
  k_router<<<2048, 256, 0, stream>>>(x, gate_w, TKI, TKW);
  k_dispatch<<<1, 256, 0, stream>>>(TKI, GRP, GRPS, SLOT, TOK, ZB);
  k_gather<<<4096, 256, 0, stream>>>(XB, TOK, BUF);

  // routed experts
  k_transpose<<<dim3(22, 32, 16), dim3(64, 4), 0, stream>>>(w_gate, WT1, 2048, 1408);
  k_transpose<<<dim3(22, 32, 16), dim3(64, 4), 0, stream>>>(w_up, WT2, 2048, 1408);
  k_gemm_gu<<<dim3(22, 8, 16), 256, 0, stream>>>(BUF, WT1, WT2, Mb, GRP, ZB, 2048, 1408);
  k_transpose<<<dim3(32, 22, 16), dim3(64, 4), 0, stream>>>(w_down, WT1, 1408, 2048);
  k_gemm_dn<<<dim3(32, 8, 16), 256, 0, stream>>>(Mb, WT1, EO, GRP, ZB, 1408, 2048);

  // shared experts
  k_transpose<<<dim3(44, 32, 1), dim3(64, 4), 0, stream>>>(ws_gate, WT1, 2048, 2816);
  k_transpose<<<dim3(44, 32, 1), dim3(64, 4), 0, stream>>>(ws_up, WT2, 2048, 2816);
  k_gemm_gu<<<dim3(44, 16, 1), 256, 0, stream>>>(XB, WT1, WT2, Mb, GRPS, ZB, 2048, 2816);
  k_transpose<<<dim3(32, 44, 1), dim3(64, 4), 0, stream>>>(ws_down, WT1, 2816, 2048);
  k_gemm_dn<<<dim3(32, 16, 1), 256, 0, stream>>>(Mb, WT1, SH, GRPS, ZB, 2816, 2048);

  // combine
  k_combine<<<4096, 256, 0, stream>>>(SH, EO, SLOT, TKW, out);
}